// Round 1
// baseline (1022.041 us; speedup 1.0000x reference)
//
#include <hip/hip_runtime.h>

#define B 8
#define N 512
#define D 128
#define H 128

#define TI 16
#define TJ 16
#define LDP 132   // pad 128 -> 132 floats: breaks same-bank aliasing on row reads

// ---------------- kernel 0: Wp = Wa + Wc, Wq = Wb - Wc ----------------
__global__ void build_w_kernel(const float* __restrict__ W1,
                               float* __restrict__ Wp, float* __restrict__ Wq) {
    int t = blockIdx.x * blockDim.x + threadIdx.x;   // 0 .. H*D-1
    if (t >= H * D) return;
    int h = t >> 7, k = t & 127;
    float wa = W1[h * 384 + k];
    float wb = W1[h * 384 + 128 + k];
    float wc = W1[h * 384 + 256 + k];
    Wp[t] = wa + wc;
    Wq[t] = wb - wc;
}

// ---------------- kernel 1: P = F0 @ Wp^T + b1,  Q = F0 @ Wq^T ----------------
// one block per (b,i) row; threads 0..127 -> P, 128..255 -> Q
__global__ __launch_bounds__(256) void pq_kernel(const float* __restrict__ F0,
                                                 const float* __restrict__ Wp,
                                                 const float* __restrict__ Wq,
                                                 const float* __restrict__ b1,
                                                 float* __restrict__ P,
                                                 float* __restrict__ Q) {
    int row = blockIdx.x;            // 0 .. B*N-1
    __shared__ float f[D];
    int tid = threadIdx.x;
    if (tid < D) f[tid] = F0[(size_t)row * D + tid];
    __syncthreads();
    int h   = tid & 127;
    int sel = tid >> 7;
    const float4* w4 = (const float4*)((sel ? Wq : Wp) + h * D);
    const float4* f4 = (const float4*)f;
    float acc = 0.f;
#pragma unroll
    for (int k4 = 0; k4 < D / 4; ++k4) {
        float4 w = w4[k4], ff = f4[k4];
        acc = fmaf(w.x, ff.x, acc);
        acc = fmaf(w.y, ff.y, acc);
        acc = fmaf(w.z, ff.z, acc);
        acc = fmaf(w.w, ff.w, acc);
    }
    if (sel) Q[(size_t)row * H + h] = acc;
    else     P[(size_t)row * H + h] = acc + b1[h];  // fold b1 into P
}

// ---------------- kernel 2: the 2.1M-pair fused MLP ----------------
__global__ __launch_bounds__(256) void pair_kernel(const float* __restrict__ P,
                                                   const float* __restrict__ Q,
                                                   const float* __restrict__ W2,
                                                   const float* __restrict__ b2,
                                                   const float* __restrict__ W3,
                                                   const float* __restrict__ b3v,
                                                   const int* __restrict__ mask,
                                                   float* __restrict__ out) {
    int b  = blockIdx.z;
    int i0 = blockIdx.y * TI;
    int j0 = blockIdx.x * TJ;
    __shared__ float Pl[TI][LDP];
    __shared__ float Ql[TJ][LDP];
    int tid = threadIdx.x;
    for (int t = tid; t < TI * H; t += 256) {
        int r = t >> 7, c = t & 127;
        Pl[r][c] = P[((size_t)(b * N) + i0 + r) * H + c];
        Ql[r][c] = Q[((size_t)(b * N) + j0 + r) * H + c];
    }
    __syncthreads();
    int ti = tid >> 4, tj = tid & 15;

    float acc[64];
#pragma unroll
    for (int o = 0; o < 64; ++o) acc[o] = 0.f;

    const float4* W2v = (const float4*)W2;   // W2[o][k] row-major (64 x 128)
#pragma unroll 1
    for (int k4 = 0; k4 < H / 4; ++k4) {
        float4 p = *(const float4*)&Pl[ti][k4 * 4];
        float4 q = *(const float4*)&Ql[tj][k4 * 4];
        float hx = fmaxf(p.x + q.x, 0.f);
        float hy = fmaxf(p.y + q.y, 0.f);
        float hz = fmaxf(p.z + q.z, 0.f);
        float hw = fmaxf(p.w + q.w, 0.f);
#pragma unroll
        for (int o = 0; o < 64; ++o) {
            float4 w = W2v[o * (H / 4) + k4];  // wave-uniform -> scalar loads
            acc[o] = fmaf(hx, w.x, acc[o]);
            acc[o] = fmaf(hy, w.y, acc[o]);
            acc[o] = fmaf(hz, w.z, acc[o]);
            acc[o] = fmaf(hw, w.w, acc[o]);
        }
    }

    float logit = b3v[0];
#pragma unroll
    for (int o = 0; o < 64; ++o) {
        float v = fmaxf(acc[o] + b2[o], 0.f);
        logit = fmaf(v, W3[o], logit);
    }

    int i = i0 + ti, j = j0 + tj;
    bool m = (mask[b * N + i] != 0) && (mask[b * N + j] != 0);
    float val = 0.f;
    if (m) val = 1.f / (1.f + expf(-logit));   // sigmoid(-1e9) == 0 exactly
    out[((size_t)(b * N) + i) * N + j] = val;
}

extern "C" void kernel_launch(void* const* d_in, const int* in_sizes, int n_in,
                              void* d_out, int out_size, void* d_ws, size_t ws_size,
                              hipStream_t stream) {
    const float* F0  = (const float*)d_in[0];
    const int*   msk = (const int*)  d_in[1];
    const float* W1  = (const float*)d_in[2];
    const float* b1  = (const float*)d_in[3];
    const float* W2  = (const float*)d_in[4];
    const float* b2  = (const float*)d_in[5];
    const float* W3  = (const float*)d_in[6];
    const float* b3  = (const float*)d_in[7];
    float* out = (float*)d_out;

    float* ws = (float*)d_ws;
    float* Wp = ws;                       // H*D        = 16384
    float* Wq = Wp + H * D;               // H*D        = 16384
    float* P  = Wq + H * D;               // B*N*H      = 524288
    float* Qb = P + (size_t)B * N * H;    // B*N*H      = 524288

    build_w_kernel<<<(H * D + 255) / 256, 256, 0, stream>>>(W1, Wp, Wq);
    pq_kernel<<<B * N, 256, 0, stream>>>(F0, Wp, Wq, b1, P, Qb);
    pair_kernel<<<dim3(N / TJ, N / TI, B), 256, 0, stream>>>(P, Qb, W2, b2, W3, b3,
                                                             msk, out);
}

// Round 2
// 125.833 us; speedup vs baseline: 8.1222x; 8.1222x over previous
//
#include <hip/hip_runtime.h>

#define B 8
#define N 512
#define D 128
#define H 128
#define IC 32     // i-rows per block
#define JT 64     // j-cols per block (4 waves x 16)

typedef __attribute__((ext_vector_type(8))) __bf16 bf16x8;
typedef __attribute__((ext_vector_type(4))) float f32x4;

// ---------------- kernel 0: Wp = Wa + Wc, Wq = Wb - Wc, W2 -> bf16 ----------------
__global__ void build_w_kernel(const float* __restrict__ W1,
                               const float* __restrict__ W2,
                               float* __restrict__ Wp, float* __restrict__ Wq,
                               __bf16* __restrict__ W2b) {
    int t = blockIdx.x * blockDim.x + threadIdx.x;   // 0 .. H*D-1
    if (t < H * D) {
        int h = t >> 7, k = t & 127;
        float wa = W1[h * 384 + k];
        float wb = W1[h * 384 + 128 + k];
        float wc = W1[h * 384 + 256 + k];
        Wp[t] = wa + wc;
        Wq[t] = wb - wc;
    }
    if (t < 64 * H) W2b[t] = (__bf16)W2[t];          // row-major [64][128]
}

// ---------------- kernel 1: P = F0 @ Wp^T + b1,  Q = F0 @ Wq^T ----------------
__global__ __launch_bounds__(256) void pq_kernel(const float* __restrict__ F0,
                                                 const float* __restrict__ Wp,
                                                 const float* __restrict__ Wq,
                                                 const float* __restrict__ b1,
                                                 float* __restrict__ P,
                                                 float* __restrict__ Q) {
    int row = blockIdx.x;            // 0 .. B*N-1
    __shared__ float f[D];
    int tid = threadIdx.x;
    if (tid < D) f[tid] = F0[(size_t)row * D + tid];
    __syncthreads();
    int h   = tid & 127;
    int sel = tid >> 7;
    const float4* w4 = (const float4*)((sel ? Wq : Wp) + h * D);
    const float4* f4 = (const float4*)f;
    float acc = 0.f;
#pragma unroll
    for (int k4 = 0; k4 < D / 4; ++k4) {
        float4 w = w4[k4], ff = f4[k4];
        acc = fmaf(w.x, ff.x, acc);
        acc = fmaf(w.y, ff.y, acc);
        acc = fmaf(w.z, ff.z, acc);
        acc = fmaf(w.w, ff.w, acc);
    }
    if (sel) Q[(size_t)row * H + h] = acc;
    else     P[(size_t)row * H + h] = acc + b1[h];  // fold b1 into P
}

// ---------------- kernel 2: fused pair MLP via bf16 MFMA ----------------
// D-tile per MFMA: rows = o (16 of 64 outputs), cols = pair (16 j's).
// A-operand = W2 (o x k), B-operand = h1^T (k x pair).
// Verified gfx950 layouts: A/B: lane holds row/col = lane&15, k = (lane>>4)*8+e.
// C/D: col = lane&15 (pair), row = (lane>>4)*4 + reg (o within group).
__global__ __launch_bounds__(256) void pair_mfma_kernel(
        const float* __restrict__ P, const float* __restrict__ Q,
        const __bf16* __restrict__ W2b,
        const float* __restrict__ b2, const float* __restrict__ W3,
        const float* __restrict__ b3v, const int* __restrict__ mask,
        float* __restrict__ out) {
    int b  = blockIdx.z;
    int i0 = blockIdx.y * IC;
    int j0 = blockIdx.x * JT;
    int tid  = threadIdx.x;
    int lane = tid & 63;
    int w    = tid >> 6;          // wave 0..3
    int lg   = lane >> 4;         // k-slice group 0..3
    int lp   = lane & 15;         // pair col / W2 row-within-group

    __shared__ float Pl[IC][128];
    __shared__ int   mI[IC];

    // stage P rows (IC*128 floats = 1024 float4, 4 per thread, coalesced)
    {
        const float4* Pg  = (const float4*)(P + ((size_t)(b * N) + i0) * H);
        float4* Pl4 = (float4*)&Pl[0][0];
#pragma unroll
        for (int t = 0; t < (IC * H / 4) / 256; ++t)
            Pl4[tid + t * 256] = Pg[tid + t * 256];
        if (tid < IC) mI[tid] = mask[b * N + i0 + tid];
    }
    __syncthreads();

    // W2 fragments: w2f[g][c] = row o=g*16+lp, k = c*32 + lg*8 .. +7
    bf16x8 w2f[4][4];
    const bf16x8* W2v = (const bf16x8*)W2b;   // 16 chunks of 8 per 128-row
#pragma unroll
    for (int g = 0; g < 4; ++g)
#pragma unroll
        for (int c = 0; c < 4; ++c)
            w2f[g][c] = W2v[(g * 16 + lp) * 16 + c * 4 + lg];

    // Q fragment source (f32): this wave's 16 j's; lane holds j = j0+w*16+lp,
    // k-slice c*32+lg*8 .. +7  -> qf[c][0..1]
    int j = j0 + w * 16 + lp;
    float4 qf[4][2];
    {
        const float4* Qg = (const float4*)(Q + ((size_t)(b * N) + j) * H);
#pragma unroll
        for (int c = 0; c < 4; ++c) {
            qf[c][0] = Qg[c * 8 + lg * 2];
            qf[c][1] = Qg[c * 8 + lg * 2 + 1];
        }
    }

    // epilogue constants: lane's o indices = g*16 + lg*4 + {0..3}
    float4 b2v[4], w3v[4];
#pragma unroll
    for (int g = 0; g < 4; ++g) {
        b2v[g] = *(const float4*)(b2 + g * 16 + lg * 4);
        w3v[g] = *(const float4*)(W3 + g * 16 + lg * 4);
    }
    float b3s = b3v[0];
    int   mj  = mask[b * N + j];

    for (int ii = 0; ii < IC; ++ii) {
        f32x4 acc[4];
#pragma unroll
        for (int g = 0; g < 4; ++g) acc[g] = 0.f;

#pragma unroll
        for (int c = 0; c < 4; ++c) {
            const float* pr = &Pl[ii][c * 32 + lg * 8];
            float4 p0 = *(const float4*)pr;          // broadcast within 16-lane group
            float4 p1 = *(const float4*)(pr + 4);
            bf16x8 hv;
            hv[0] = (__bf16)fmaxf(p0.x + qf[c][0].x, 0.f);
            hv[1] = (__bf16)fmaxf(p0.y + qf[c][0].y, 0.f);
            hv[2] = (__bf16)fmaxf(p0.z + qf[c][0].z, 0.f);
            hv[3] = (__bf16)fmaxf(p0.w + qf[c][0].w, 0.f);
            hv[4] = (__bf16)fmaxf(p1.x + qf[c][1].x, 0.f);
            hv[5] = (__bf16)fmaxf(p1.y + qf[c][1].y, 0.f);
            hv[6] = (__bf16)fmaxf(p1.z + qf[c][1].z, 0.f);
            hv[7] = (__bf16)fmaxf(p1.w + qf[c][1].w, 0.f);
#pragma unroll
            for (int g = 0; g < 4; ++g)
                acc[g] = __builtin_amdgcn_mfma_f32_16x16x32_bf16(w2f[g][c], hv,
                                                                 acc[g], 0, 0, 0);
        }

        // epilogue: logit = sum_o relu(h2[o]+b2[o]) * W3[o]  (lane covers 16 o's)
        float lr = 0.f;
#pragma unroll
        for (int g = 0; g < 4; ++g) {
            lr = fmaf(fmaxf(acc[g][0] + b2v[g].x, 0.f), w3v[g].x, lr);
            lr = fmaf(fmaxf(acc[g][1] + b2v[g].y, 0.f), w3v[g].y, lr);
            lr = fmaf(fmaxf(acc[g][2] + b2v[g].z, 0.f), w3v[g].z, lr);
            lr = fmaf(fmaxf(acc[g][3] + b2v[g].w, 0.f), w3v[g].w, lr);
        }
        lr += __shfl_xor(lr, 16);
        lr += __shfl_xor(lr, 32);

        float logit = lr + b3s;
        bool  m     = (mI[ii] != 0) && (mj != 0);
        float val   = m ? 1.f / (1.f + __expf(-logit)) : 0.f;

        if (lane < 16)
            out[((size_t)(b * N) + i0 + ii) * N + j0 + w * 16 + lane] = val;
    }
}

extern "C" void kernel_launch(void* const* d_in, const int* in_sizes, int n_in,
                              void* d_out, int out_size, void* d_ws, size_t ws_size,
                              hipStream_t stream) {
    const float* F0  = (const float*)d_in[0];
    const int*   msk = (const int*)  d_in[1];
    const float* W1  = (const float*)d_in[2];
    const float* b1  = (const float*)d_in[3];
    const float* W2  = (const float*)d_in[4];
    const float* b2  = (const float*)d_in[5];
    const float* W3  = (const float*)d_in[6];
    const float* b3  = (const float*)d_in[7];
    float* out = (float*)d_out;

    float* ws = (float*)d_ws;
    float*  Wp  = ws;                        // 16384
    float*  Wq  = Wp + H * D;                // 16384
    float*  P   = Wq + H * D;                // 524288
    float*  Qb  = P + (size_t)B * N * H;     // 524288
    __bf16* W2b = (__bf16*)(Qb + (size_t)B * N * H);  // 8192 bf16

    build_w_kernel<<<(H * D + 255) / 256, 256, 0, stream>>>(W1, W2, Wp, Wq, W2b);
    pq_kernel<<<B * N, 256, 0, stream>>>(F0, Wp, Wq, b1, P, Qb);
    pair_mfma_kernel<<<dim3(N / JT, N / IC, B), 256, 0, stream>>>(
        P, Qb, W2b, b2, W3, b3, msk, out);
}

// Round 4
// 60.066 us; speedup vs baseline: 17.0154x; 2.0949x over previous
//
#include <hip/hip_runtime.h>

#define B 8
#define N 512
#define D 128
#define H 128
#define IC 32     // i-rows per block (pair kernel)
#define JT 64     // j-cols per block (4 waves x 16)

typedef __attribute__((ext_vector_type(8))) _Float16 f16x8;
typedef __attribute__((ext_vector_type(4))) float f32x4;

union F8 { uint4 u; f16x8 f; };

// ---------------- kernel 0: build Wpq (f16), W2h (f16), b1e (f32) ----------------
// Wpq[256][128]: rows 0-127 = Wa+Wc, rows 128-255 = Wb-Wc
// b1e[256]: b1 for cols 0-127, 0 for cols 128-255
__global__ void build_w_kernel(const float* __restrict__ W1,
                               const float* __restrict__ W2,
                               const float* __restrict__ b1,
                               _Float16* __restrict__ Wpq,
                               _Float16* __restrict__ W2h,
                               float* __restrict__ b1e) {
    int t = blockIdx.x * blockDim.x + threadIdx.x;   // 0 .. 16383
    if (t < H * D) {
        int h = t >> 7, k = t & 127;
        float wa = W1[h * 384 + k];
        float wb = W1[h * 384 + 128 + k];
        float wc = W1[h * 384 + 256 + k];
        Wpq[h * 128 + k]         = (_Float16)(wa + wc);
        Wpq[(128 + h) * 128 + k] = (_Float16)(wb - wc);
    }
    if (t < 64 * H) W2h[t] = (_Float16)W2[t];
    if (t < 256)    b1e[t] = (t < 128) ? b1[t] : 0.f;
}

// ---------------- kernel 1: PQ = f16( F0 @ Wpq^T + b1e ) via f16 MFMA ----------------
// one wave per block; block covers 16 rows x 64 cols
__global__ __launch_bounds__(64) void pq_mfma_kernel(const float* __restrict__ F0,
                                                     const _Float16* __restrict__ Wpq,
                                                     const float* __restrict__ b1e,
                                                     _Float16* __restrict__ PQ) {
    int r0 = blockIdx.x * 16;        // F0 row base (0..4080)
    int cb = blockIdx.y * 64;        // output col base (0..192)
    int lane = threadIdx.x;
    int lp = lane & 15, lg = lane >> 4;

    // A-fragments: row = r0+lp, k = ks*32 + lg*8 .. +7  (f32 -> f16)
    f16x8 af[4];
    const float* fr = F0 + (size_t)(r0 + lp) * D;
#pragma unroll
    for (int ks = 0; ks < 4; ++ks) {
        float4 a0 = *(const float4*)(fr + ks * 32 + lg * 8);
        float4 a1 = *(const float4*)(fr + ks * 32 + lg * 8 + 4);
        f16x8 v;
        v[0] = (_Float16)a0.x; v[1] = (_Float16)a0.y;
        v[2] = (_Float16)a0.z; v[3] = (_Float16)a0.w;
        v[4] = (_Float16)a1.x; v[5] = (_Float16)a1.y;
        v[6] = (_Float16)a1.z; v[7] = (_Float16)a1.w;
        af[ks] = v;
    }

#pragma unroll
    for (int ct = 0; ct < 4; ++ct) {
        int col = cb + ct * 16 + lp;
        const _Float16* wrow = Wpq + (size_t)col * 128;
        f32x4 acc = 0.f;
#pragma unroll
        for (int ks = 0; ks < 4; ++ks) {
            f16x8 bf = *(const f16x8*)(wrow + ks * 32 + lg * 8);
            acc = __builtin_amdgcn_mfma_f32_16x16x32_f16(af[ks], bf, acc, 0, 0, 0);
        }
        float b1v = b1e[col];
#pragma unroll
        for (int e = 0; e < 4; ++e) {
            int row = r0 + lg * 4 + e;
            PQ[(size_t)row * 256 + col] = (_Float16)(acc[e] + b1v);
        }
    }
}

// ---------------- kernel 2: fused pair MLP, f16 MFMA ----------------
// a = W2h (o x k), b = h1 (k x pair); h1 = elementwise_max(P+Q, 0) -- packed f16
__global__ __launch_bounds__(256) void pair_mfma_kernel(
        const _Float16* __restrict__ PQ,
        const _Float16* __restrict__ W2h,
        const float* __restrict__ b2, const float* __restrict__ W3,
        const float* __restrict__ b3v, const int* __restrict__ mask,
        float* __restrict__ out) {
    int b  = blockIdx.z;
    int i0 = blockIdx.y * IC;
    int j0 = blockIdx.x * JT;
    int tid  = threadIdx.x;
    int lane = tid & 63;
    int w    = tid >> 6;          // wave 0..3
    int lg   = lane >> 4;         // k-slice group 0..3
    int lp   = lane & 15;         // pair col / o row-within-group

    __shared__ uint4 Pl[IC][16];  // P rows as f16: [row][16B chunk]
    __shared__ int   mI[IC];

    // stage P halves of PQ rows i0..i0+31 (32 rows x 16 uint4)
    {
#pragma unroll
        for (int it = 0; it < 2; ++it) {
            int r = (tid >> 4) + it * 16;
            int c = tid & 15;
            Pl[r][c] = *(const uint4*)(PQ + ((size_t)(b * N) + i0 + r) * 256 + c * 8);
        }
        if (tid < IC) mI[tid] = mask[b * N + i0 + tid];
    }
    __syncthreads();

    // W2 fragments: w2f[g][c] = row o=g*16+lp, k = c*32 + lg*8 .. +7
    F8 w2f[4][4];
#pragma unroll
    for (int g = 0; g < 4; ++g)
#pragma unroll
        for (int c = 0; c < 4; ++c)
            w2f[g][c].u = *(const uint4*)(W2h + (size_t)(g * 16 + lp) * 128 + c * 32 + lg * 8);

    // Q fragments: lane's pair j = j0 + w*16 + lp; qf[c] = Q[j][c*32+lg*8 .. +7]
    int j = j0 + w * 16 + lp;
    F8 qf[4];
    {
        const _Float16* qrow = PQ + ((size_t)(b * N) + j) * 256 + 128;
#pragma unroll
        for (int c = 0; c < 4; ++c)
            qf[c].u = *(const uint4*)(qrow + c * 32 + lg * 8);
    }

    // epilogue constants: lane's o indices = g*16 + lg*4 + {0..3}
    float4 b2v[4], w3v[4];
#pragma unroll
    for (int g = 0; g < 4; ++g) {
        b2v[g] = *(const float4*)(b2 + g * 16 + lg * 4);
        w3v[g] = *(const float4*)(W3 + g * 16 + lg * 4);
    }
    float b3s = b3v[0];
    int   mj  = mask[b * N + j];

    for (int ii = 0; ii < IC; ++ii) {
        f32x4 acc[4];
#pragma unroll
        for (int g = 0; g < 4; ++g) acc[g] = 0.f;

#pragma unroll
        for (int c = 0; c < 4; ++c) {
            F8 ph; ph.u = Pl[ii][c * 4 + lg];   // broadcast within 16-lane group
            f16x8 hv = __builtin_elementwise_max(ph.f + qf[c].f, (f16x8)(_Float16)0);
#pragma unroll
            for (int g = 0; g < 4; ++g)
                acc[g] = __builtin_amdgcn_mfma_f32_16x16x32_f16(w2f[g][c].f, hv,
                                                                acc[g], 0, 0, 0);
        }

        // logit = sum_o relu(h2[o]+b2[o]) * W3[o]   (lane covers 16 o's)
        float lr = 0.f;
#pragma unroll
        for (int g = 0; g < 4; ++g) {
            lr = fmaf(fmaxf(acc[g][0] + b2v[g].x, 0.f), w3v[g].x, lr);
            lr = fmaf(fmaxf(acc[g][1] + b2v[g].y, 0.f), w3v[g].y, lr);
            lr = fmaf(fmaxf(acc[g][2] + b2v[g].z, 0.f), w3v[g].z, lr);
            lr = fmaf(fmaxf(acc[g][3] + b2v[g].w, 0.f), w3v[g].w, lr);
        }
        lr += __shfl_xor(lr, 16);
        lr += __shfl_xor(lr, 32);

        float logit = lr + b3s;
        bool  m     = (mI[ii] != 0) && (mj != 0);
        float val   = m ? 1.f / (1.f + __expf(-logit)) : 0.f;

        if (lane < 16)
            out[((size_t)(b * N) + i0 + ii) * N + j0 + w * 16 + lane] = val;
    }
}

extern "C" void kernel_launch(void* const* d_in, const int* in_sizes, int n_in,
                              void* d_out, int out_size, void* d_ws, size_t ws_size,
                              hipStream_t stream) {
    const float* F0  = (const float*)d_in[0];
    const int*   msk = (const int*)  d_in[1];
    const float* W1  = (const float*)d_in[2];
    const float* b1  = (const float*)d_in[3];
    const float* W2  = (const float*)d_in[4];
    const float* b2  = (const float*)d_in[5];
    const float* W3  = (const float*)d_in[6];
    const float* b3  = (const float*)d_in[7];
    float* out = (float*)d_out;

    char* ws = (char*)d_ws;
    _Float16* PQ  = (_Float16*)ws;                    // 4096*256*2 = 2 MB
    _Float16* Wpq = (_Float16*)(ws + (2u << 20));     // 64 KB
    _Float16* W2h = (_Float16*)(ws + (2u << 20) + (64u << 10));  // 16 KB
    float*    b1e = (float*)   (ws + (2u << 20) + (80u << 10));  // 1 KB

    build_w_kernel<<<64, 256, 0, stream>>>(W1, W2, b1, Wpq, W2h, b1e);
    pq_mfma_kernel<<<dim3(B * N / 16, 4), 64, 0, stream>>>(F0, Wpq, b1e, PQ);
    pair_mfma_kernel<<<dim3(N / JT, N / IC, B), 256, 0, stream>>>(
        PQ, W2h, b2, W3, b3, msk, out);
}

// Round 5
// 57.461 us; speedup vs baseline: 17.7866x; 1.0453x over previous
//
#include <hip/hip_runtime.h>

#define B 8
#define N 512
#define D 128
#define H 128
#define IC 32     // i-rows per block (pair kernel)
#define JT 64     // j-cols per block (4 waves x 16)

typedef __attribute__((ext_vector_type(8))) _Float16 f16x8;
typedef __attribute__((ext_vector_type(4))) float f32x4;
typedef __attribute__((ext_vector_type(2))) float f32x2;

union F8 { uint4 u; f16x8 f; };

// ---------------- kernel 0: build Wpq (f16), W2h (f16), b1e (f32) ----------------
__global__ void build_w_kernel(const float* __restrict__ W1,
                               const float* __restrict__ W2,
                               const float* __restrict__ b1,
                               _Float16* __restrict__ Wpq,
                               _Float16* __restrict__ W2h,
                               float* __restrict__ b1e) {
    int t = blockIdx.x * blockDim.x + threadIdx.x;   // 0 .. 16383
    if (t < H * D) {
        int h = t >> 7, k = t & 127;
        float wa = W1[h * 384 + k];
        float wb = W1[h * 384 + 128 + k];
        float wc = W1[h * 384 + 256 + k];
        Wpq[h * 128 + k]         = (_Float16)(wa + wc);
        Wpq[(128 + h) * 128 + k] = (_Float16)(wb - wc);
    }
    if (t < 64 * H) W2h[t] = (_Float16)W2[t];
    if (t < 256)    b1e[t] = (t < 128) ? b1[t] : 0.f;
}

// ---------------- kernel 1: PQ = f16( F0 @ Wpq^T + b1e ) via f16 MFMA ----------------
__global__ __launch_bounds__(64) void pq_mfma_kernel(const float* __restrict__ F0,
                                                     const _Float16* __restrict__ Wpq,
                                                     const float* __restrict__ b1e,
                                                     _Float16* __restrict__ PQ) {
    int r0 = blockIdx.x * 16;        // F0 row base
    int cb = blockIdx.y * 64;        // output col base
    int lane = threadIdx.x;
    int lp = lane & 15, lg = lane >> 4;

    f16x8 af[4];
    const float* fr = F0 + (size_t)(r0 + lp) * D;
#pragma unroll
    for (int ks = 0; ks < 4; ++ks) {
        float4 a0 = *(const float4*)(fr + ks * 32 + lg * 8);
        float4 a1 = *(const float4*)(fr + ks * 32 + lg * 8 + 4);
        f16x8 v;
        v[0] = (_Float16)a0.x; v[1] = (_Float16)a0.y;
        v[2] = (_Float16)a0.z; v[3] = (_Float16)a0.w;
        v[4] = (_Float16)a1.x; v[5] = (_Float16)a1.y;
        v[6] = (_Float16)a1.z; v[7] = (_Float16)a1.w;
        af[ks] = v;
    }

#pragma unroll
    for (int ct = 0; ct < 4; ++ct) {
        int col = cb + ct * 16 + lp;
        const _Float16* wrow = Wpq + (size_t)col * 128;
        f32x4 acc = 0.f;
#pragma unroll
        for (int ks = 0; ks < 4; ++ks) {
            f16x8 bf = *(const f16x8*)(wrow + ks * 32 + lg * 8);
            acc = __builtin_amdgcn_mfma_f32_16x16x32_f16(af[ks], bf, acc, 0, 0, 0);
        }
        float b1v = b1e[col];
#pragma unroll
        for (int e = 0; e < 4; ++e) {
            int row = r0 + lg * 4 + e;
            PQ[(size_t)row * 256 + col] = (_Float16)(acc[e] + b1v);
        }
    }
}

// ---------------- kernel 2: fused pair MLP, f16 MFMA, ii-unroll x2 ----------------
__global__ __launch_bounds__(256) void pair_mfma_kernel(
        const _Float16* __restrict__ PQ,
        const _Float16* __restrict__ W2h,
        const float* __restrict__ b2, const float* __restrict__ W3,
        const float* __restrict__ b3v, const int* __restrict__ mask,
        float* __restrict__ out) {
    int b  = blockIdx.z;
    int i0 = blockIdx.y * IC;
    int j0 = blockIdx.x * JT;
    int tid  = threadIdx.x;
    int lane = tid & 63;
    int w    = tid >> 6;          // wave 0..3
    int lg   = lane >> 4;         // k-slice group 0..3
    int lp   = lane & 15;         // pair col / o row-within-group

    __shared__ uint4 Pl[IC][16];  // P rows as f16: [row][16B chunk]
    __shared__ int   mI[IC];

    {
#pragma unroll
        for (int it = 0; it < 2; ++it) {
            int r = (tid >> 4) + it * 16;
            int c = tid & 15;
            Pl[r][c] = *(const uint4*)(PQ + ((size_t)(b * N) + i0 + r) * 256 + c * 8);
        }
        if (tid < IC) mI[tid] = mask[b * N + i0 + tid];
    }
    __syncthreads();

    // W2 fragments: w2f[g][c] = row o=g*16+lp, k = c*32 + lg*8 .. +7
    F8 w2f[4][4];
#pragma unroll
    for (int g = 0; g < 4; ++g)
#pragma unroll
        for (int c = 0; c < 4; ++c)
            w2f[g][c].u = *(const uint4*)(W2h + (size_t)(g * 16 + lp) * 128 + c * 32 + lg * 8);

    // Q fragments: lane's pair j = j0 + w*16 + lp
    int j = j0 + w * 16 + lp;
    F8 qf[4];
    {
        const _Float16* qrow = PQ + ((size_t)(b * N) + j) * 256 + 128;
#pragma unroll
        for (int c = 0; c < 4; ++c)
            qf[c].u = *(const uint4*)(qrow + c * 32 + lg * 8);
    }

    // epilogue constants: lane's o indices = g*16 + lg*4 + {0..3}
    f32x4 b2v[4], w3v[4];
#pragma unroll
    for (int g = 0; g < 4; ++g) {
        b2v[g] = *(const f32x4*)(b2 + g * 16 + lg * 4);
        w3v[g] = *(const f32x4*)(W3 + g * 16 + lg * 4);
    }
    float b3s = b3v[0];
    int   mj  = mask[b * N + j];
    const f32x4 z4 = 0.f;
    const f16x8 zh = (f16x8)(_Float16)0;

    size_t outrow = ((size_t)(b * N) + i0) * N + j0 + w * 16 + (lane & 15);

    for (int ii = 0; ii < IC; ii += 2) {
        f32x4 acc0[4], acc1[4];
#pragma unroll
        for (int g = 0; g < 4; ++g) { acc0[g] = 0.f; acc1[g] = 0.f; }

#pragma unroll
        for (int c = 0; c < 4; ++c) {
            F8 ph0, ph1;
            ph0.u = Pl[ii][c * 4 + lg];
            ph1.u = Pl[ii + 1][c * 4 + lg];
            f16x8 hv0 = __builtin_elementwise_max(ph0.f + qf[c].f, zh);
            f16x8 hv1 = __builtin_elementwise_max(ph1.f + qf[c].f, zh);
#pragma unroll
            for (int g = 0; g < 4; ++g) {
                acc0[g] = __builtin_amdgcn_mfma_f32_16x16x32_f16(w2f[g][c].f, hv0,
                                                                 acc0[g], 0, 0, 0);
                acc1[g] = __builtin_amdgcn_mfma_f32_16x16x32_f16(w2f[g][c].f, hv1,
                                                                 acc1[g], 0, 0, 0);
            }
        }

        // packed-f32 epilogue for both i's
        f32x4 lr40 = 0.f, lr41 = 0.f;
#pragma unroll
        for (int g = 0; g < 4; ++g) {
            f32x4 t0 = __builtin_elementwise_max(acc0[g] + b2v[g], z4);
            f32x4 t1 = __builtin_elementwise_max(acc1[g] + b2v[g], z4);
            lr40 = __builtin_elementwise_fma(t0, w3v[g], lr40);
            lr41 = __builtin_elementwise_fma(t1, w3v[g], lr41);
        }
        float lr0 = (lr40.x + lr40.y) + (lr40.z + lr40.w);
        float lr1 = (lr41.x + lr41.y) + (lr41.z + lr41.w);
        lr0 += __shfl_xor(lr0, 16);
        lr0 += __shfl_xor(lr0, 32);
        lr1 += __shfl_xor(lr1, 16);
        lr1 += __shfl_xor(lr1, 32);

        float logit0 = lr0 + b3s;
        float logit1 = lr1 + b3s;
        bool  m0 = (mI[ii] != 0)     && (mj != 0);
        bool  m1 = (mI[ii + 1] != 0) && (mj != 0);
        float v0 = m0 ? 1.f / (1.f + __expf(-logit0)) : 0.f;
        float v1 = m1 ? 1.f / (1.f + __expf(-logit1)) : 0.f;

        if (lane < 16) {
            out[outrow + (size_t)ii * N]       = v0;
            out[outrow + (size_t)(ii + 1) * N] = v1;
        }
    }
}

extern "C" void kernel_launch(void* const* d_in, const int* in_sizes, int n_in,
                              void* d_out, int out_size, void* d_ws, size_t ws_size,
                              hipStream_t stream) {
    const float* F0  = (const float*)d_in[0];
    const int*   msk = (const int*)  d_in[1];
    const float* W1  = (const float*)d_in[2];
    const float* b1  = (const float*)d_in[3];
    const float* W2  = (const float*)d_in[4];
    const float* b2  = (const float*)d_in[5];
    const float* W3  = (const float*)d_in[6];
    const float* b3  = (const float*)d_in[7];
    float* out = (float*)d_out;

    char* ws = (char*)d_ws;
    _Float16* PQ  = (_Float16*)ws;                    // 2 MB
    _Float16* Wpq = (_Float16*)(ws + (2u << 20));     // 64 KB
    _Float16* W2h = (_Float16*)(ws + (2u << 20) + (64u << 10));  // 16 KB
    float*    b1e = (float*)   (ws + (2u << 20) + (80u << 10));  // 1 KB

    build_w_kernel<<<64, 256, 0, stream>>>(W1, W2, b1, Wpq, W2h, b1e);
    pq_mfma_kernel<<<dim3(B * N / 16, 4), 64, 0, stream>>>(F0, Wpq, b1e, PQ);
    pair_mfma_kernel<<<dim3(N / JT, N / IC, B), 256, 0, stream>>>(
        PQ, W2h, b2, W3, b3, msk, out);
}